// Round 1
// baseline (17796.106 us; speedup 1.0000x reference)
//
#include <hip/hip_runtime.h>
#include <hip/hip_bf16.h>

#define NN 1000000
#define D_INF 57
#define D_OUTF 128

__device__ __forceinline__ float ldT(const float* p){ return *p; }
__device__ __forceinline__ float ldT(const __hip_bfloat16* p){ return __bfloat162float(*p); }
__device__ __forceinline__ void stT(float* p, float v){ *p = v; }
__device__ __forceinline__ void stT(__hip_bfloat16* p, float v){ *p = __float2bfloat16(v); }

// ---------------- Layer 1: x[1M,57] -> h1[1M,128] ----------------
// block = 256 threads, 16 nodes/block. LDS: W1^T [114][128] (58 KB) + comb.
template<typename TH>
__global__ __launch_bounds__(256, 2) void sage_layer1(
    const float* __restrict__ x, const float* __restrict__ W1,
    const int* __restrict__ nidx, const int* __restrict__ nmask,
    TH* __restrict__ h1)
{
  __shared__ float w1s[114 * 128];    // [j][c], c contiguous -> conflict-free
  __shared__ float comb[16][120];     // [node][114], padded
  __shared__ float red[4];
  const int t = threadIdx.x;

  // Stage W1 transposed: W1 is [128][114] row-major.
  for (int e = t; e < 128 * 114; e += 256) {
    int c = e / 114;
    int j = e - c * 114;
    w1s[j * 128 + c] = W1[e];
  }

  const int base = blockIdx.x * 16;

  // Phase A: build combined = [self(57) | masked-mean(57)] for 16 nodes.
  for (int w = t; w < 16 * 57; w += 256) {
    int n = w / 57;
    int j = w - n * 57;
    int node = base + n;
    int i0 = nidx[node * 3 + 0], i1 = nidx[node * 3 + 1], i2 = nidx[node * 3 + 2];
    int m0 = nmask[node * 3 + 0], m1 = nmask[node * 3 + 1], m2 = nmask[node * 3 + 2];
    float s = 0.f;
    if (m0) s += x[(long)i0 * 57 + j];
    if (m1) s += x[(long)i1 * 57 + j];
    if (m2) s += x[(long)i2 * 57 + j];
    int cnt = m0 + m1 + m2; if (cnt < 1) cnt = 1;
    comb[n][j]      = x[(long)node * 57 + j];
    comb[n][57 + j] = s / (float)cnt;
  }
  __syncthreads();

  // Phase B: 2 nodes at a time; thread -> (node-half, channel).
  const int c = t & 127;
  const int half = t >> 7;
  const int wave = t >> 6;
  for (int nn = 0; nn < 16; nn += 2) {
    int n = nn + half;
    const float* cb = comb[n];
    float a0 = 0.f, a1 = 0.f, a2 = 0.f;
    #pragma unroll
    for (int j = 0; j < 114; j += 3) {
      a0 = fmaf(cb[j],     w1s[(j)     * 128 + c], a0);
      a1 = fmaf(cb[j + 1], w1s[(j + 1) * 128 + c], a1);
      a2 = fmaf(cb[j + 2], w1s[(j + 2) * 128 + c], a2);
    }
    float v = fmaxf(a0 + a1 + a2, 0.f);
    // L2 norm over the node's 128 channels (2 waves).
    float sq = v * v;
    #pragma unroll
    for (int o = 32; o > 0; o >>= 1) sq += __shfl_xor(sq, o);
    __syncthreads();                       // red reuse guard
    if ((t & 63) == 0) red[wave] = sq;
    __syncthreads();
    float norm2 = red[half * 2] + red[half * 2 + 1];
    float inv = 1.0f / fmaxf(sqrtf(norm2), 1e-12f);
    stT(&h1[(long)(base + n) * 128 + c], v * inv);
  }
}

// ---------------- Layer 2: h1[1M,128] -> out[1M,128] ----------------
// block = 256 threads, 8 nodes/block. LDS: W2^T [256][128] (128 KB) + comb.
template<typename TH>
__global__ __launch_bounds__(256, 1) void sage_layer2(
    const TH* __restrict__ h1, const float* __restrict__ W2,
    const int* __restrict__ nidx, const int* __restrict__ nmask,
    float* __restrict__ out)
{
  __shared__ float w2s[256 * 128];    // [k][c]
  __shared__ float comb[8][256];
  __shared__ float red[4];
  const int t = threadIdx.x;

  for (int e = t; e < 128 * 256; e += 256) {
    int c = e >> 8;
    int k = e & 255;
    w2s[k * 128 + c] = W2[e];
  }

  const int base = blockIdx.x * 8;

  for (int w = t; w < 8 * 128; w += 256) {
    int n = w >> 7;
    int j = w & 127;
    int node = base + n;
    int i0 = nidx[node * 3 + 0], i1 = nidx[node * 3 + 1], i2 = nidx[node * 3 + 2];
    int m0 = nmask[node * 3 + 0], m1 = nmask[node * 3 + 1], m2 = nmask[node * 3 + 2];
    float s = 0.f;
    if (m0) s += ldT(&h1[(long)i0 * 128 + j]);
    if (m1) s += ldT(&h1[(long)i1 * 128 + j]);
    if (m2) s += ldT(&h1[(long)i2 * 128 + j]);
    int cnt = m0 + m1 + m2; if (cnt < 1) cnt = 1;
    comb[n][j]       = ldT(&h1[(long)node * 128 + j]);
    comb[n][128 + j] = s / (float)cnt;
  }
  __syncthreads();

  const int c = t & 127;
  const int half = t >> 7;
  const int wave = t >> 6;
  for (int nn = 0; nn < 8; nn += 2) {
    int n = nn + half;
    const float* cb = comb[n];
    float a0 = 0.f, a1 = 0.f, a2 = 0.f, a3 = 0.f;
    #pragma unroll
    for (int j = 0; j < 256; j += 4) {
      a0 = fmaf(cb[j],     w2s[(j)     * 128 + c], a0);
      a1 = fmaf(cb[j + 1], w2s[(j + 1) * 128 + c], a1);
      a2 = fmaf(cb[j + 2], w2s[(j + 2) * 128 + c], a2);
      a3 = fmaf(cb[j + 3], w2s[(j + 3) * 128 + c], a3);
    }
    float v = fmaxf((a0 + a1) + (a2 + a3), 0.f);
    float sq = v * v;
    #pragma unroll
    for (int o = 32; o > 0; o >>= 1) sq += __shfl_xor(sq, o);
    __syncthreads();
    if ((t & 63) == 0) red[wave] = sq;
    __syncthreads();
    float norm2 = red[half * 2] + red[half * 2 + 1];
    float inv = 1.0f / fmaxf(sqrtf(norm2), 1e-12f);
    out[(long)(base + n) * 128 + c] = v * inv;
  }
}

extern "C" void kernel_launch(void* const* d_in, const int* in_sizes, int n_in,
                              void* d_out, int out_size, void* d_ws, size_t ws_size,
                              hipStream_t stream) {
  const float* x   = (const float*)d_in[0];
  const float* W1  = (const float*)d_in[1];
  const float* W2  = (const float*)d_in[2];
  const int* idx1  = (const int*)d_in[3];
  const int* msk1  = (const int*)d_in[4];
  const int* idx2  = (const int*)d_in[5];
  const int* msk2  = (const int*)d_in[6];
  float* out = (float*)d_out;

  if (ws_size >= (size_t)NN * 128 * sizeof(float)) {
    float* h1 = (float*)d_ws;
    sage_layer1<float><<<NN / 16, 256, 0, stream>>>(x, W1, idx1, msk1, h1);
    sage_layer2<float><<<NN / 8, 256, 0, stream>>>(h1, W2, idx2, msk2, out);
  } else {
    __hip_bfloat16* h1 = (__hip_bfloat16*)d_ws;
    sage_layer1<__hip_bfloat16><<<NN / 16, 256, 0, stream>>>(x, W1, idx1, msk1, h1);
    sage_layer2<__hip_bfloat16><<<NN / 8, 256, 0, stream>>>(h1, W2, idx2, msk2, out);
  }
}

// Round 2
// 1276.918 us; speedup vs baseline: 13.9368x; 13.9368x over previous
//
#include <hip/hip_runtime.h>
#include <hip/hip_bf16.h>

#define NN 1000000
#define NG 15625   // NN / 64 nodes per group

typedef short bf16x8 __attribute__((ext_vector_type(8)));
typedef float f32x4  __attribute__((ext_vector_type(4)));
typedef unsigned short u16x8 __attribute__((ext_vector_type(8)));

__device__ __forceinline__ float bf2f(unsigned short u){
  unsigned int x = ((unsigned int)u) << 16; float f;
  __builtin_memcpy(&f, &x, 4); return f;
}
__device__ __forceinline__ short f2bf(float v){
  __hip_bfloat16 h = __float2bfloat16(v); short s;
  __builtin_memcpy(&s, &h, 2); return s;
}

// ---------------- Layer 2: h1(bf16)[1M,128] -> out(f32)[1M,128] ----------------
// 256 thr = 4 waves; group = 64 nodes; wave w owns cols [w*32, w*32+32).
// B = W2^T kept entirely in VGPRs (frags loaded once). LDS: swizzled comb tile.
__global__ __launch_bounds__(256, 2) void sage2_mfma(
    const unsigned short* __restrict__ h1, const float* __restrict__ W2,
    const int* __restrict__ nidx, const int* __restrict__ nmask,
    float* __restrict__ out)
{
  __shared__ unsigned short comb[64 * 256];   // [node][k] bf16, XOR-swizzled
  __shared__ float red[64][4];
  const int t   = threadIdx.x;
  const int l   = t & 63;
  const int w   = t >> 6;
  const int cfr = l & 15;     // MFMA row/col-in-frag lane id
  const int kg  = l >> 4;     // k-group 0..3

  // --- B fragments (bf16) in registers: Bf[ks][nf], col = w*32+nf*16+cfr ---
  bf16x8 Bf[8][2];
  #pragma unroll
  for (int ks = 0; ks < 8; ++ks) {
    #pragma unroll
    for (int nf = 0; nf < 2; ++nf) {
      const int col = w*32 + nf*16 + cfr;
      const int k0  = ks*32 + kg*8;
      const float* p = W2 + col*256 + k0;          // 16B aligned
      f32x4 a = *reinterpret_cast<const f32x4*>(p);
      f32x4 b = *reinterpret_cast<const f32x4*>(p + 4);
      bf16x8 v;
      v[0]=f2bf(a[0]); v[1]=f2bf(a[1]); v[2]=f2bf(a[2]); v[3]=f2bf(a[3]);
      v[4]=f2bf(b[0]); v[5]=f2bf(b[1]); v[6]=f2bf(b[2]); v[7]=f2bf(b[3]);
      Bf[ks][nf] = v;
    }
  }

  const u16x8* hp = reinterpret_cast<const u16x8*>(h1);  // 16B chunks of h1 rows
  char* cb = reinterpret_cast<char*>(comb);

  // gather stash (registers), 4 items/thread: item = (node n, 16B-chunk q)
  u16x8 sS[4], s0[4], s1[4], s2[4];
  float m0[4], m1[4], m2[4], iv[4];

  auto ISSUE = [&](int g){
    const long gb = (long)g * 64;
    #pragma unroll
    for (int i = 0; i < 4; ++i) {
      int it = t + i*256;
      int n = it >> 4, q = it & 15;
      long node = gb + n;
      int j0 = nidx[node*3+0], j1 = nidx[node*3+1], j2 = nidx[node*3+2];
      int b0 = nmask[node*3+0], b1 = nmask[node*3+1], b2 = nmask[node*3+2];
      m0[i]=(float)b0; m1[i]=(float)b1; m2[i]=(float)b2;
      int c = b0+b1+b2; iv[i] = 1.0f/(float)(c<1?1:c);
      u16x8 z = {};
      sS[i] = hp[node*16 + q];
      s0[i] = b0 ? hp[(long)j0*16 + q] : z;
      s1[i] = b1 ? hp[(long)j1*16 + q] : z;
      s2[i] = b2 ? hp[(long)j2*16 + q] : z;
    }
  };

  int g0 = blockIdx.x;
  if (g0 < NG) ISSUE(g0);

  for (int g = blockIdx.x; g < NG; g += gridDim.x) {
    const long gb = (long)g * 64;
    // unpack stash -> swizzled comb
    #pragma unroll
    for (int i = 0; i < 4; ++i) {
      int it = t + i*256;
      int n = it >> 4, q = it & 15;
      int sw = (n & 7) << 4;
      *reinterpret_cast<u16x8*>(cb + n*512 + ((q*16) ^ sw)) = sS[i];
      u16x8 r;
      #pragma unroll
      for (int j = 0; j < 8; ++j)
        r[j] = (unsigned short)f2bf(
            (m0[i]*bf2f(s0[i][j]) + m1[i]*bf2f(s1[i][j]) + m2[i]*bf2f(s2[i][j])) * iv[i]);
      *reinterpret_cast<u16x8*>(cb + n*512 + ((256 + q*16) ^ sw)) = r;
    }
    __syncthreads();

    int gn = g + gridDim.x;
    if (gn < NG) ISSUE(gn);          // loads in flight across the MFMA phase

    f32x4 acc[4][2];
    #pragma unroll
    for (int r = 0; r < 4; ++r) {
      acc[r][0] = (f32x4){0.f,0.f,0.f,0.f};
      acc[r][1] = (f32x4){0.f,0.f,0.f,0.f};
    }
    const int sw = (cfr & 7) << 4;
    #pragma unroll
    for (int r = 0; r < 4; ++r) {
      const int rb = (r*16 + cfr) * 512;
      #pragma unroll
      for (int ks = 0; ks < 8; ++ks) {
        bf16x8 af = *reinterpret_cast<const bf16x8*>(cb + rb + ((ks*64 + kg*16) ^ sw));
        acc[r][0] = __builtin_amdgcn_mfma_f32_16x16x32_bf16(af, Bf[ks][0], acc[r][0], 0,0,0);
        acc[r][1] = __builtin_amdgcn_mfma_f32_16x16x32_bf16(af, Bf[ks][1], acc[r][1], 0,0,0);
      }
    }

    // relu, partial sum-of-squares over this wave's 32 cols, 16-lane reduce
    float ssv[4][4];
    #pragma unroll
    for (int r = 0; r < 4; ++r) {
      #pragma unroll
      for (int e = 0; e < 4; ++e) {
        float v0 = fmaxf(acc[r][0][e], 0.f); acc[r][0][e] = v0;
        float v1 = fmaxf(acc[r][1][e], 0.f); acc[r][1][e] = v1;
        float s = v0*v0 + v1*v1;
        s += __shfl_xor(s, 1); s += __shfl_xor(s, 2);
        s += __shfl_xor(s, 4); s += __shfl_xor(s, 8);
        ssv[r][e] = s;
      }
      if (cfr < 4) {   // static-select to avoid runtime reg-array index
        float v = cfr==0 ? ssv[r][0] : cfr==1 ? ssv[r][1] : cfr==2 ? ssv[r][2] : ssv[r][3];
        red[r*16 + kg*4 + cfr][w] = v;
      }
    }
    __syncthreads();

    #pragma unroll
    for (int r = 0; r < 4; ++r) {
      #pragma unroll
      for (int e = 0; e < 4; ++e) {
        int row = r*16 + kg*4 + e;
        float tot = red[row][0] + red[row][1] + red[row][2] + red[row][3];
        float inv = 1.0f / fmaxf(sqrtf(tot), 1e-12f);
        long node = gb + row;
        out[node*128 + w*32 + cfr]      = acc[r][0][e] * inv;
        out[node*128 + w*32 + 16 + cfr] = acc[r][1][e] * inv;
      }
    }
  }
}

// ---------------- Layer 1: x(f32)[1M,57] -> h1(bf16)[1M,128] ----------------
// combined = [self(57)|agg(57)] padded to K=128 (pad zeros in both B and comb).
__global__ __launch_bounds__(256, 2) void sage1_mfma(
    const float* __restrict__ x, const float* __restrict__ W1,
    const int* __restrict__ nidx, const int* __restrict__ nmask,
    unsigned short* __restrict__ h1)
{
  __shared__ unsigned short comb[64 * 128];
  __shared__ float red[64][4];
  const int t   = threadIdx.x;
  const int l   = t & 63;
  const int w   = t >> 6;
  const int cfr = l & 15;
  const int kg  = l >> 4;

  bf16x8 Bf[4][2];
  #pragma unroll
  for (int ks = 0; ks < 4; ++ks) {
    #pragma unroll
    for (int nf = 0; nf < 2; ++nf) {
      const int col = w*32 + nf*16 + cfr;
      const int k0  = ks*32 + kg*8;
      bf16x8 v;
      #pragma unroll
      for (int j = 0; j < 8; ++j) {
        int k = k0 + j;
        v[j] = (k < 114) ? f2bf(W1[col*114 + k]) : (short)0;
      }
      Bf[ks][nf] = v;
    }
  }

  char* cb = reinterpret_cast<char*>(comb);
  // zero the pad region k=114..127 once (gather never touches it)
  for (int e = t; e < 64*14; e += 256) {
    int n = e / 14, k = 114 + (e - (e/14)*14);
    *reinterpret_cast<unsigned short*>(cb + n*256 + ((2*k) ^ ((n&7)<<4))) = 0;
  }

  for (int g = blockIdx.x; g < NG; g += gridDim.x) {
    const long gb = (long)g * 64;
    for (int it = t; it < 64*57; it += 256) {
      int n = it / 57, j = it - (it/57)*57;
      long node = gb + n;
      int j0 = nidx[node*3+0], j1 = nidx[node*3+1], j2 = nidx[node*3+2];
      int b0 = nmask[node*3+0], b1 = nmask[node*3+1], b2 = nmask[node*3+2];
      int c = b0+b1+b2; float ivc = 1.0f/(float)(c<1?1:c);
      float self = x[node*57 + j];
      float s = 0.f;
      if (b0) s += x[(long)j0*57 + j];
      if (b1) s += x[(long)j1*57 + j];
      if (b2) s += x[(long)j2*57 + j];
      s *= ivc;
      int sw = (n&7)<<4;
      *reinterpret_cast<unsigned short*>(cb + n*256 + ((2*j) ^ sw))      = (unsigned short)f2bf(self);
      *reinterpret_cast<unsigned short*>(cb + n*256 + ((2*(57+j)) ^ sw)) = (unsigned short)f2bf(s);
    }
    __syncthreads();

    f32x4 acc[4][2];
    #pragma unroll
    for (int r = 0; r < 4; ++r) {
      acc[r][0] = (f32x4){0.f,0.f,0.f,0.f};
      acc[r][1] = (f32x4){0.f,0.f,0.f,0.f};
    }
    const int sw = (cfr & 7) << 4;
    #pragma unroll
    for (int r = 0; r < 4; ++r) {
      const int rb = (r*16 + cfr) * 256;
      #pragma unroll
      for (int ks = 0; ks < 4; ++ks) {
        bf16x8 af = *reinterpret_cast<const bf16x8*>(cb + rb + ((ks*64 + kg*16) ^ sw));
        acc[r][0] = __builtin_amdgcn_mfma_f32_16x16x32_bf16(af, Bf[ks][0], acc[r][0], 0,0,0);
        acc[r][1] = __builtin_amdgcn_mfma_f32_16x16x32_bf16(af, Bf[ks][1], acc[r][1], 0,0,0);
      }
    }

    float ssv[4][4];
    #pragma unroll
    for (int r = 0; r < 4; ++r) {
      #pragma unroll
      for (int e = 0; e < 4; ++e) {
        float v0 = fmaxf(acc[r][0][e], 0.f); acc[r][0][e] = v0;
        float v1 = fmaxf(acc[r][1][e], 0.f); acc[r][1][e] = v1;
        float s = v0*v0 + v1*v1;
        s += __shfl_xor(s, 1); s += __shfl_xor(s, 2);
        s += __shfl_xor(s, 4); s += __shfl_xor(s, 8);
        ssv[r][e] = s;
      }
      if (cfr < 4) {
        float v = cfr==0 ? ssv[r][0] : cfr==1 ? ssv[r][1] : cfr==2 ? ssv[r][2] : ssv[r][3];
        red[r*16 + kg*4 + cfr][w] = v;
      }
    }
    __syncthreads();

    #pragma unroll
    for (int r = 0; r < 4; ++r) {
      #pragma unroll
      for (int e = 0; e < 4; ++e) {
        int row = r*16 + kg*4 + e;
        float tot = red[row][0] + red[row][1] + red[row][2] + red[row][3];
        float inv = 1.0f / fmaxf(sqrtf(tot), 1e-12f);
        long node = gb + row;
        h1[node*128 + w*32 + cfr]      = (unsigned short)f2bf(acc[r][0][e] * inv);
        h1[node*128 + w*32 + 16 + cfr] = (unsigned short)f2bf(acc[r][1][e] * inv);
      }
    }
  }
}

extern "C" void kernel_launch(void* const* d_in, const int* in_sizes, int n_in,
                              void* d_out, int out_size, void* d_ws, size_t ws_size,
                              hipStream_t stream) {
  const float* x   = (const float*)d_in[0];
  const float* W1  = (const float*)d_in[1];
  const float* W2  = (const float*)d_in[2];
  const int* idx1  = (const int*)d_in[3];
  const int* msk1  = (const int*)d_in[4];
  const int* idx2  = (const int*)d_in[5];
  const int* msk2  = (const int*)d_in[6];
  float* out = (float*)d_out;
  unsigned short* h1 = (unsigned short*)d_ws;   // bf16 [1M,128] = 256 MB (fits, per round 0)

  sage1_mfma<<<1024, 256, 0, stream>>>(x, W1, idx1, msk1, h1);
  sage2_mfma<<<512,  256, 0, stream>>>(h1, W2, idx2, msk2, out);
}

// Round 3
// 735.701 us; speedup vs baseline: 24.1893x; 1.7356x over previous
//
#include <hip/hip_runtime.h>
#include <hip/hip_bf16.h>

#define NN 1000000
#define NG 15625   // NN / 64 nodes per group

typedef short bf16x8 __attribute__((ext_vector_type(8)));
typedef float f32x4  __attribute__((ext_vector_type(4)));
typedef unsigned short u16x8 __attribute__((ext_vector_type(8)));
typedef unsigned short u16x4 __attribute__((ext_vector_type(4)));

__device__ __forceinline__ float bf2f(unsigned short u){
  unsigned int x = ((unsigned int)u) << 16; float f;
  __builtin_memcpy(&f, &x, 4); return f;
}
__device__ __forceinline__ short f2bf(float v){
  __hip_bfloat16 h = __float2bfloat16(v); short s;
  __builtin_memcpy(&s, &h, 2); return s;
}

// ---------------- Layer 2: h1(bf16)[1M,128] -> out(f32)[1M,128] ----------------
__global__ __launch_bounds__(256, 2) void sage2_mfma(
    const unsigned short* __restrict__ h1, const float* __restrict__ W2,
    const int* __restrict__ nidx, const int* __restrict__ nmask,
    float* __restrict__ out)
{
  __shared__ unsigned short comb[64 * 256];   // [node][k] bf16, XOR-swizzled
  __shared__ float red[64][4];
  const int t   = threadIdx.x;
  const int l   = t & 63;
  const int w   = t >> 6;
  const int cfr = l & 15;
  const int kg  = l >> 4;

  bf16x8 Bf[8][2];
  #pragma unroll
  for (int ks = 0; ks < 8; ++ks) {
    #pragma unroll
    for (int nf = 0; nf < 2; ++nf) {
      const int col = w*32 + nf*16 + cfr;
      const int k0  = ks*32 + kg*8;
      const float* p = W2 + col*256 + k0;
      f32x4 a = *reinterpret_cast<const f32x4*>(p);
      f32x4 b = *reinterpret_cast<const f32x4*>(p + 4);
      bf16x8 v;
      v[0]=f2bf(a[0]); v[1]=f2bf(a[1]); v[2]=f2bf(a[2]); v[3]=f2bf(a[3]);
      v[4]=f2bf(b[0]); v[5]=f2bf(b[1]); v[6]=f2bf(b[2]); v[7]=f2bf(b[3]);
      Bf[ks][nf] = v;
    }
  }

  const u16x8* hp = reinterpret_cast<const u16x8*>(h1);
  char* cb = reinterpret_cast<char*>(comb);

  u16x8 sS[4], s0[4], s1[4], s2[4];
  float m0[4], m1[4], m2[4], iv[4];

  auto ISSUE = [&](int g){
    const long gb = (long)g * 64;
    #pragma unroll
    for (int i = 0; i < 4; ++i) {
      int it = t + i*256;
      int n = it >> 4, q = it & 15;
      long node = gb + n;
      int j0 = nidx[node*3+0], j1 = nidx[node*3+1], j2 = nidx[node*3+2];
      int b0 = nmask[node*3+0], b1 = nmask[node*3+1], b2 = nmask[node*3+2];
      m0[i]=(float)b0; m1[i]=(float)b1; m2[i]=(float)b2;
      int c = b0+b1+b2; iv[i] = 1.0f/(float)(c<1?1:c);
      u16x8 z = {};
      sS[i] = hp[node*16 + q];
      s0[i] = b0 ? hp[(long)j0*16 + q] : z;
      s1[i] = b1 ? hp[(long)j1*16 + q] : z;
      s2[i] = b2 ? hp[(long)j2*16 + q] : z;
    }
  };

  if (blockIdx.x < NG) ISSUE(blockIdx.x);

  for (int g = blockIdx.x; g < NG; g += gridDim.x) {
    const long gb = (long)g * 64;
    #pragma unroll
    for (int i = 0; i < 4; ++i) {
      int it = t + i*256;
      int n = it >> 4, q = it & 15;
      int sw = (n & 7) << 4;
      *reinterpret_cast<u16x8*>(cb + n*512 + ((q*16) ^ sw)) = sS[i];
      u16x8 r;
      #pragma unroll
      for (int j = 0; j < 8; ++j)
        r[j] = (unsigned short)f2bf(
            (m0[i]*bf2f(s0[i][j]) + m1[i]*bf2f(s1[i][j]) + m2[i]*bf2f(s2[i][j])) * iv[i]);
      *reinterpret_cast<u16x8*>(cb + n*512 + ((256 + q*16) ^ sw)) = r;
    }
    __syncthreads();

    int gn = g + gridDim.x;
    if (gn < NG) ISSUE(gn);

    f32x4 acc[4][2];
    #pragma unroll
    for (int r = 0; r < 4; ++r) {
      acc[r][0] = (f32x4){0.f,0.f,0.f,0.f};
      acc[r][1] = (f32x4){0.f,0.f,0.f,0.f};
    }
    const int sw = (cfr & 7) << 4;
    #pragma unroll
    for (int r = 0; r < 4; ++r) {
      const int rb = (r*16 + cfr) * 512;
      #pragma unroll
      for (int ks = 0; ks < 8; ++ks) {
        bf16x8 af = *reinterpret_cast<const bf16x8*>(cb + rb + ((ks*64 + kg*16) ^ sw));
        acc[r][0] = __builtin_amdgcn_mfma_f32_16x16x32_bf16(af, Bf[ks][0], acc[r][0], 0,0,0);
        acc[r][1] = __builtin_amdgcn_mfma_f32_16x16x32_bf16(af, Bf[ks][1], acc[r][1], 0,0,0);
      }
    }

    float ssv[4][4];
    #pragma unroll
    for (int r = 0; r < 4; ++r) {
      #pragma unroll
      for (int e = 0; e < 4; ++e) {
        float v0 = fmaxf(acc[r][0][e], 0.f); acc[r][0][e] = v0;
        float v1 = fmaxf(acc[r][1][e], 0.f); acc[r][1][e] = v1;
        float s = v0*v0 + v1*v1;
        s += __shfl_xor(s, 1); s += __shfl_xor(s, 2);
        s += __shfl_xor(s, 4); s += __shfl_xor(s, 8);
        ssv[r][e] = s;
      }
      if (cfr < 4) {
        float v = cfr==0 ? ssv[r][0] : cfr==1 ? ssv[r][1] : cfr==2 ? ssv[r][2] : ssv[r][3];
        red[r*16 + kg*4 + cfr][w] = v;
      }
    }
    __syncthreads();

    #pragma unroll
    for (int r = 0; r < 4; ++r) {
      #pragma unroll
      for (int e = 0; e < 4; ++e) {
        int row = r*16 + kg*4 + e;
        float tot = red[row][0] + red[row][1] + red[row][2] + red[row][3];
        float inv = 1.0f / fmaxf(sqrtf(tot), 1e-12f);
        long node = gb + row;
        out[node*128 + w*32 + cfr]      = acc[r][0][e] * inv;
        out[node*128 + w*32 + 16 + cfr] = acc[r][1][e] * inv;
      }
    }
  }
}

// ---------------- Layer 1: x(f32)[1M,57] -> h1(bf16)[1M,128] ----------------
// LDS K-layout: [0,57)=self j, [57,64)=0, [64,121)=agg j, [121,128)=0.
// item = (node n, quad q): 4 floats j=4q..4q+3; two aligned 8B LDS stores.
__global__ __launch_bounds__(256, 2) void sage1_mfma(
    const float* __restrict__ x, const float* __restrict__ W1,
    const int* __restrict__ nidx, const int* __restrict__ nmask,
    unsigned short* __restrict__ h1)
{
  __shared__ unsigned short comb[64 * 128];
  __shared__ float red[64][4];
  const int t   = threadIdx.x;
  const int l   = t & 63;
  const int w   = t >> 6;
  const int cfr = l & 15;
  const int kg  = l >> 4;

  // B fragments with remapped K: lds_k<57 -> W k=lds_k; 64<=lds_k<121 -> W k=lds_k-7.
  bf16x8 Bf[4][2];
  #pragma unroll
  for (int ks = 0; ks < 4; ++ks) {
    #pragma unroll
    for (int nf = 0; nf < 2; ++nf) {
      const int col = w*32 + nf*16 + cfr;
      const int k0  = ks*32 + kg*8;
      bf16x8 v;
      #pragma unroll
      for (int j = 0; j < 8; ++j) {
        int lk = k0 + j;
        int wk = lk < 64 ? lk : lk - 7;
        bool valid = (lk < 57) || (lk >= 64 && lk < 121);
        v[j] = valid ? f2bf(W1[col*114 + wk]) : (short)0;
      }
      Bf[ks][nf] = v;
    }
  }

  char* cb = reinterpret_cast<char*>(comb);

  f32x4 sf[4], n0[4], n1[4], n2[4];
  float m0[4], m1[4], m2[4], iv[4];

  auto ISSUE = [&](int g){
    const long gb = (long)g * 64;
    #pragma unroll
    for (int i = 0; i < 4; ++i) {
      int it = t + i*256;
      int n = it >> 4, q = it & 15;
      long node = gb + n;
      int j0 = nidx[node*3+0], j1 = nidx[node*3+1], j2 = nidx[node*3+2];
      int b0 = nmask[node*3+0], b1 = nmask[node*3+1], b2 = nmask[node*3+2];
      m0[i]=(float)b0; m1[i]=(float)b1; m2[i]=(float)b2;
      int c = b0+b1+b2; iv[i] = 1.0f/(float)(c<1?1:c);
      #pragma unroll
      for (int jj = 0; jj < 4; ++jj) {
        int j = q*4 + jj;
        bool jv = j < 57;
        sf[i][jj] = jv            ? x[node*57 + j]       : 0.f;
        n0[i][jj] = (b0 && jv)    ? x[(long)j0*57 + j]   : 0.f;
        n1[i][jj] = (b1 && jv)    ? x[(long)j1*57 + j]   : 0.f;
        n2[i][jj] = (b2 && jv)    ? x[(long)j2*57 + j]   : 0.f;
      }
    }
  };

  if (blockIdx.x < NG) ISSUE(blockIdx.x);

  for (int g = blockIdx.x; g < NG; g += gridDim.x) {
    const long gb = (long)g * 64;
    #pragma unroll
    for (int i = 0; i < 4; ++i) {
      int it = t + i*256;
      int n = it >> 4, q = it & 15;
      int sw = (n & 7) << 4;
      u16x4 vs, va;
      #pragma unroll
      for (int jj = 0; jj < 4; ++jj) {
        vs[jj] = (unsigned short)f2bf(sf[i][jj]);
        va[jj] = (unsigned short)f2bf(
            (m0[i]*n0[i][jj] + m1[i]*n1[i][jj] + m2[i]*n2[i][jj]) * iv[i]);
      }
      *reinterpret_cast<u16x4*>(cb + n*256 + ((q*8) ^ sw))        = vs;
      *reinterpret_cast<u16x4*>(cb + n*256 + ((128 + q*8) ^ sw))  = va;
    }
    __syncthreads();

    int gn = g + gridDim.x;
    if (gn < NG) ISSUE(gn);

    f32x4 acc[4][2];
    #pragma unroll
    for (int r = 0; r < 4; ++r) {
      acc[r][0] = (f32x4){0.f,0.f,0.f,0.f};
      acc[r][1] = (f32x4){0.f,0.f,0.f,0.f};
    }
    const int sw = (cfr & 7) << 4;
    #pragma unroll
    for (int r = 0; r < 4; ++r) {
      const int rb = (r*16 + cfr) * 256;
      #pragma unroll
      for (int ks = 0; ks < 4; ++ks) {
        bf16x8 af = *reinterpret_cast<const bf16x8*>(cb + rb + ((ks*64 + kg*16) ^ sw));
        acc[r][0] = __builtin_amdgcn_mfma_f32_16x16x32_bf16(af, Bf[ks][0], acc[r][0], 0,0,0);
        acc[r][1] = __builtin_amdgcn_mfma_f32_16x16x32_bf16(af, Bf[ks][1], acc[r][1], 0,0,0);
      }
    }

    float ssv[4][4];
    #pragma unroll
    for (int r = 0; r < 4; ++r) {
      #pragma unroll
      for (int e = 0; e < 4; ++e) {
        float v0 = fmaxf(acc[r][0][e], 0.f); acc[r][0][e] = v0;
        float v1 = fmaxf(acc[r][1][e], 0.f); acc[r][1][e] = v1;
        float s = v0*v0 + v1*v1;
        s += __shfl_xor(s, 1); s += __shfl_xor(s, 2);
        s += __shfl_xor(s, 4); s += __shfl_xor(s, 8);
        ssv[r][e] = s;
      }
      if (cfr < 4) {
        float v = cfr==0 ? ssv[r][0] : cfr==1 ? ssv[r][1] : cfr==2 ? ssv[r][2] : ssv[r][3];
        red[r*16 + kg*4 + cfr][w] = v;
      }
    }
    __syncthreads();

    #pragma unroll
    for (int r = 0; r < 4; ++r) {
      #pragma unroll
      for (int e = 0; e < 4; ++e) {
        int row = r*16 + kg*4 + e;
        float tot = red[row][0] + red[row][1] + red[row][2] + red[row][3];
        float inv = 1.0f / fmaxf(sqrtf(tot), 1e-12f);
        long node = gb + row;
        h1[node*128 + w*32 + cfr]      = (unsigned short)f2bf(acc[r][0][e] * inv);
        h1[node*128 + w*32 + 16 + cfr] = (unsigned short)f2bf(acc[r][1][e] * inv);
      }
    }
  }
}

extern "C" void kernel_launch(void* const* d_in, const int* in_sizes, int n_in,
                              void* d_out, int out_size, void* d_ws, size_t ws_size,
                              hipStream_t stream) {
  const float* x   = (const float*)d_in[0];
  const float* W1  = (const float*)d_in[1];
  const float* W2  = (const float*)d_in[2];
  const int* idx1  = (const int*)d_in[3];
  const int* msk1  = (const int*)d_in[4];
  const int* idx2  = (const int*)d_in[5];
  const int* msk2  = (const int*)d_in[6];
  float* out = (float*)d_out;
  unsigned short* h1 = (unsigned short*)d_ws;   // bf16 [1M,128] = 256 MB

  sage1_mfma<<<2048, 256, 0, stream>>>(x, W1, idx1, msk1, h1);
  sage2_mfma<<<1024, 256, 0, stream>>>(h1, W2, idx2, msk2, out);
}